// Round 10
// baseline (312.061 us; speedup 1.0000x reference)
//
#include <hip/hip_runtime.h>
#include <hip/hip_bf16.h>

// ---------------------------------------------------------------------------
// SFMCNN r9: component-best config. conv2 = r1 structure + original rotation
// (74.4us, best of 4 measured variants). conv3 = 4-phase named-reg pipeline +
// original rotation (best). NEW: fc K-split coarsened 432xK256 -> 216xK512 —
// halves the part intermediate (24.8->12.4MB write + read-back), red1 depth
// 54->27. conv1/prep unchanged.
//
// ws layout (float offsets): unchanged.
//   p1u  [0, 8306688)          bf16 (3,128,26,26,64) halo-baked; h3bf aliases
//   p2u  [8306688, +4816896)   bf16 (3,128,14,14,128) halo-baked
//   S2   [13123584, +221184)   S3 [13344768, +55296)  wsq [13400064, +1344)
//   w2s  [13401408, +110592)   w3s [13512000, +442368)
//   part [13954368, +3096576 used)  part2 [20147520, +102400)
//   w1s/swq1 alias the head of part (dead until fc_kernel).
// ---------------------------------------------------------------------------

static const size_t OFF_P2CL = 8306688;
static const size_t OFF_S2   = 13123584;
static const size_t OFF_S3   = 13344768;
static const size_t OFF_WSQ  = 13400064;
static const size_t OFF_W2S  = 13401408;
static const size_t OFF_W3S  = 13512000;
static const size_t OFF_PART = 13954368;
static const size_t OFF_PART2= 20147520;

typedef short bf16x8 __attribute__((ext_vector_type(8)));
typedef float f32x4 __attribute__((ext_vector_type(4)));

__device__ __forceinline__ unsigned short f2bf(float f) {
    union { float f; unsigned u; } v; v.f = f;
    unsigned r = (v.u + 0x7FFFu + ((v.u >> 16) & 1u)) >> 16;
    return (unsigned short)r;
}
__device__ __forceinline__ float bf2f(unsigned short h) {
    union { unsigned u; float f; } v; v.u = ((unsigned)h) << 16;
    return v.f;
}
__device__ __forceinline__ unsigned pkbf(float a, float b) {
    union { __hip_bfloat162 h2; unsigned u; } c;
    c.h2 = __float22bfloat162_rn(make_float2(a, b));
    return c.u;
}
// async 16B/lane global->LDS; lds must be wave-uniform base (lane*16 implicit)
__device__ __forceinline__ void async16(void* lds, const void* g) {
    __builtin_amdgcn_global_load_lds(
        (const __attribute__((address_space(1))) unsigned*)g,
        (__attribute__((address_space(3))) unsigned*)lds, 16, 0, 0);
}

// ------------------------- prep: reorders + wsq + w1s + S3 zero ------------
__global__ __launch_bounds__(256) void prep_kernel(
        const float* __restrict__ W1, const float* __restrict__ W2,
        const float* __restrict__ W3,
        unsigned short* __restrict__ w1s, unsigned short* __restrict__ w2s,
        unsigned short* __restrict__ w3s,
        float* __restrict__ wsq, float* __restrict__ swq1,
        float* __restrict__ S3) {
    int gid = blockIdx.x * 256 + threadIdx.x;   // grid 432 -> 110592 threads
#pragma unroll
    for (int k = 0; k < 2; ++k) {               // W2s: (t,kk,co128,ci64)
        int e = gid * 2 + k;
        int t = e / 73728, r = e % 73728;
        int kk = r / 8192; r %= 8192;
        int co = r / 64, ci = r % 64;
        w2s[e] = f2bf(W2[(size_t)(t * 128 + co) * 576 + ci * 9 + kk]);
    }
#pragma unroll
    for (int k = 0; k < 8; ++k) {               // W3s: (t,kk,co256,ci128)
        int e = gid * 8 + k;
        int t = e / 294912, r = e % 294912;
        int kk = r / 32768; r %= 32768;
        int co = r / 128, ci = r % 128;
        w3s[e] = f2bf(W3[(size_t)(t * 256 + co) * 1152 + ci * 9 + kk]);
    }
    if (gid < 55296) S3[gid] = 0.f;
    // wsq: one wave per weight row (384 W2 rows len 576, 768 W3 rows len 1152)
    int wid = gid >> 6, lane = gid & 63;
    if (wid < 1152) {
        const float* wp; float* dst; int len;
        if (wid < 384) { wp = W2 + (size_t)wid * 576; len = 576; dst = wsq + 192 + wid; }
        else { wp = W3 + (size_t)(wid - 384) * 1152; len = 1152; dst = wsq + 576 + (wid - 384); }
        float s = 0.f;
        for (int k = lane; k < len; k += 64) { float v = bf2f(f2bf(wp[k])); s += v * v; }
#pragma unroll
        for (int m = 1; m < 64; m <<= 1) s += __shfl_xor(s, m, 64);
        if (lane == 0) *dst = s;
    }
    // w1s: (t,co) rows of 40 bf16 (25 taps + 15 zeros) + swq1
    if (gid < 192) {
        const float* wp = W1 + (size_t)(gid / 64) * 1600 + (gid % 64) * 25;
        unsigned short* dst = w1s + gid * 40;
        float s = 0.f;
        for (int k = 0; k < 25; ++k) {
            unsigned short u = f2bf(wp[k]);
            dst[k] = u; float v = bf2f(u); s += v * v;
        }
        for (int k = 25; k < 40; ++k) dst[k] = 0;
        swq1[gid] = s;
    }
}

// ------------------------- conv1: direct-fragment MFMA, fused pool + S2 ----
// grid (384 imgs, 12 tile-rows), block 192 = 3 waves, wave = 4 tiles of 4x4.
// LDS: simg [14][56] u16 (rows ty*4-2..+5 real, 8..13 zero) + sB 64x40 bf16.
__global__ __launch_bounds__(192, 6) void conv1_kernel(
        const float* __restrict__ x,
        const unsigned short* __restrict__ w1s, const float* __restrict__ swq1,
        const float* __restrict__ triw, const float* __restrict__ crb,
        const float* __restrict__ alp,
        unsigned short* __restrict__ p1u, float* __restrict__ S2) {
    __shared__ unsigned short simg[14 * 56];    // 1568 B
    __shared__ unsigned short sB[64 * 40];      // 5120 B

    int bi = blockIdx.x;
    int ty = blockIdx.y;                        // tile row 0..11
    int t = bi / 128, b = bi % 128;
    int tid = threadIdx.x;
    int w = tid >> 6, l = tid & 63;
    int lm = l & 15, q = l >> 4;
    const float* xim = x + (size_t)(b * 3 + t) * 2304;

    // stage weights (bf16-packed in prep) via async global->LDS
    {
        const unsigned short* wsrc = w1s + (size_t)t * 2560;
        for (int c = w; c < 5; c += 3)
            async16((char*)sB + c * 1024, wsrc + c * 512 + l * 8);
    }
    // stage image strip: rows 0..7 = gy ty*4-2..ty*4+5, rows 8..13 zero
    for (int idx = tid; idx < 14 * 56; idx += 192) {
        int rl = idx / 56, cc = idx % 56;
        int gy = ty * 4 - 2 + rl, gx = cc - 2;
        float v = (rl < 8 && cc < 52 && gy >= 0 && gy < 48 && gx >= 0 && gx < 48)
                      ? xim[gy * 48 + gx] : 0.f;
        simg[idx] = f2bf(v);
    }
    __syncthreads();

    f32x4 zz; zz[0] = 0.f; zz[1] = 0.f; zz[2] = 0.f; zz[3] = 0.f;
    bf16x8 bF[4];
#pragma unroll
    for (int nt = 0; nt < 4; ++nt)
        bF[nt] = *(const bf16x8*)(&sB[(nt * 16 + lm) * 40 + q * 8]);
    float wqv[4];
#pragma unroll
    for (int nt = 0; nt < 4; ++nt) wqv[nt] = swq1[t * 64 + nt * 16 + lm];

    float tw = triw[t * 3 + 0], itw = 1.f / tw;
    float cb = crb[t * 3 + 0];
    float al = alp[t * 2 + 0];
    int qa = q & 1;
    float aw0 = qa ? al * 0.25f : al * al * al * 0.25f;   // r even
    float aw1 = qa ? 0.25f      : al * al * 0.25f;        // r odd
    size_t imgbase = (size_t)bi * 43264;
    int py_g = ty * 2 + (q >> 1);
    int dx = q & 1;
    int kq = q * 8;

#pragma unroll
    for (int mt = 0; mt < 4; ++mt) {
        int tx = w * 4 + mt;
        // ---- A fragment build: row = lm (pos within tile), k-slice = q*8.. ----
        int base = ((lm >> 2) * 56 + tx * 4 + (lm & 3)) * 2;   // byte
        unsigned short rv[8];
        float sq = 0.f;
#pragma unroll
        for (int j = 0; j < 8; ++j) {
            int k = kq + j;
            int ky = (k * 205) >> 10;                 // k/5 for k<32
            int boff = 2 * k + 102 * ky;              // (ky*56 + kx)*2
            boff = (k < 25) ? boff : 10 * 112;        // k>=25 -> zero row 10
            unsigned short u = *(const unsigned short*)((const char*)simg + base + boff);
            rv[j] = u;
            float v = bf2f(u);
            sq = fmaf(v, v, sq);
        }
        sq += __shfl_xor(sq, 16, 64);
        sq += __shfl_xor(sq, 32, 64);                 // xsq of position (tx, lm)
        union { bf16x8 v; unsigned u[4]; } aF;
#pragma unroll
        for (int jj = 0; jj < 4; ++jj)
            aF.u[jj] = (unsigned)rv[2 * jj] | ((unsigned)rv[2 * jj + 1] << 16);

        f32x4 acc[4];
#pragma unroll
        for (int nt = 0; nt < 4; ++nt)
            acc[nt] = __builtin_amdgcn_mfma_f32_16x16x32_bf16(aF.v, bF[nt], zz, 0, 0, 0);

        float xr[4];
#pragma unroll
        for (int r = 0; r < 4; ++r) xr[r] = __shfl(sq, q * 4 + r, 64);

        float s2l0 = 0.f, s2l1 = 0.f;
        unsigned short pu0[4], pu1[4];
#pragma unroll
        for (int nt = 0; nt < 4; ++nt) {
            float hw[4];
#pragma unroll
            for (int r = 0; r < 4; ++r) {
                float d = fmaf(-2.f, acc[nt][r], xr[r]) + wqv[nt];
                d = fminf(fmaxf(d, 0.f), tw);
                float h = 1.f - d * itw;
                h = (h >= cb) ? h : 0.f;
                hw[r] = h * ((r & 1) ? aw1 : aw0);
            }
            float ph0 = hw[0] + hw[1], ph1 = hw[2] + hw[3];
            float p0 = ph0 + __shfl_xor(ph0, 16, 64);
            float p1 = ph1 + __shfl_xor(ph1, 16, 64);
            unsigned short u0 = f2bf(p0), u1 = f2bf(p1);
            float v0 = bf2f(u0), v1 = bf2f(u1);
            s2l0 += v0 * v0;
            s2l1 += v1 * v1;
            pu0[nt] = u0; pu1[nt] = u1;
        }
#pragma unroll
        for (int m2 = 1; m2 < 16; m2 <<= 1) {
            s2l0 += __shfl_xor(s2l0, m2, 64);
            s2l1 += __shfl_xor(s2l1, m2, 64);
        }
        int cell = (py_g + 1) * 26 + tx * 2 + 1 + dx;
#pragma unroll
        for (int nt = 0; nt < 4; ++nt)
            p1u[imgbase + (size_t)cell * 64 + nt * 16 + lm] = dx ? pu1[nt] : pu0[nt];
        if (lm == 0)
            S2[(size_t)bi * 576 + py_g * 24 + tx * 2 + dx] = dx ? s2l1 : s2l0;
    }

    // border zeros: 800 uint4 writes per img, split over 12 ty blocks
    if (tid < 68) {
        int e = ty * 68 + tid;
        if (e < 800) {
            int bc = e >> 3, c8 = e & 7;
            int cell;
            if (bc < 26) cell = bc;
            else if (bc < 52) cell = 650 + (bc - 26);
            else { int r = bc - 52; cell = (1 + (r >> 1)) * 26 + ((r & 1) * 25); }
            uint4 z; z.x = 0; z.y = 0; z.z = 0; z.w = 0;
            *(uint4*)(p1u + imgbase + (size_t)cell * 64 + c8 * 8) = z;
        }
    }
}

// ------------------------- conv2: half-image MFMA, fused pool + S3 ---------
// grid (768 = 384img x 2 halves, 2 co-halves), block 576 = 9 waves.
// M=288 (18 tiles of 4x4 conv points), N=64, K = 2ks x 9kk x 32ci.
// LDS: img [0,27648) 1728x16B swizzled; w [27648,64512) 2304x16B swizzled;
//      sS 64512 (364 f), sxqm 65968 (288 f), swq 67120 (64 f). total 67376 B.
// r1 structure, original rotation — best measured (74.4us).
__global__ __launch_bounds__(576, 5) void conv2_kernel(
        const unsigned short* __restrict__ p1u, const unsigned short* __restrict__ w2s,
        const float* __restrict__ S2, const float* __restrict__ triw,
        const float* __restrict__ crb, const float* __restrict__ alp,
        const float* __restrict__ wsq, unsigned short* __restrict__ p2u,
        float* __restrict__ S3) {
    extern __shared__ char sm[];
    float* sS   = (float*)(sm + 64512);
    float* sxqm = (float*)(sm + 65968);
    float* swq  = (float*)(sm + 67120);

    int ih = blockIdx.x;
    int i = ih >> 1, h = ih & 1;
    int t = i / 128;
    int co0 = blockIdx.y * 64;
    int tid = threadIdx.x;
    int w = tid >> 6, l = tid & 63;
    int lm = l & 15, q = l >> 4;

    for (int e = tid; e < 364; e += 576) {
        int rl = e / 26, cc = e % 26;
        int gy = 12 * h + rl - 1, gx = cc - 1;
        sS[e] = (gy >= 0 && gy < 24 && gx >= 0 && gx < 24)
                    ? S2[(size_t)i * 576 + gy * 24 + gx] : 0.f;
    }
    if (tid < 64) swq[tid] = wsq[192 + t * 128 + co0 + tid];
    __syncthreads();
    if (tid < 288) {
        int tile = tid >> 4, idx = tid & 15;
        int by = tile / 6, bx = tile % 6;
        int oy = by * 4 + (idx >> 2), ox = bx * 4 + (idx & 3);
        float s = 0.f;
#pragma unroll
        for (int ky = 0; ky < 3; ++ky)
#pragma unroll
            for (int kx = 0; kx < 3; ++kx) s += sS[(oy + ky) * 26 + ox + kx];
        sxqm[tid] = s;
    }

    int posA[2];
#pragma unroll
    for (int mt = 0; mt < 2; ++mt) {
        int tile = w * 2 + mt;
        int by = tile / 6, bx = tile % 6;
        posA[mt] = (by * 4 + (lm >> 2)) * 26 + bx * 4 + (lm & 3);
    }

    f32x4 zz; zz[0] = 0.f; zz[1] = 0.f; zz[2] = 0.f; zz[3] = 0.f;
    f32x4 acc[2][4];
#pragma unroll
    for (int a = 0; a < 2; ++a)
#pragma unroll
        for (int bb = 0; bb < 4; ++bb) acc[a][bb] = zz;

    for (int ks = 0; ks < 2; ++ks) {
        __syncthreads();
        // img: 364 cells x 4 chunks (32ci half), swizzled
#pragma unroll
        for (int it = 0; it < 3; ++it) {
            int L = it * 576 + tid;
            int Lc = (L < 1456) ? L : 0;
            int cell = Lc >> 2, pos = Lc & 3;
            const unsigned short* g = p1u + ((size_t)i * 676 + cell + h * 312) * 64
                                      + ks * 32 + (((pos - cell) & 3) << 3);
            async16(sm + ((L & ~63) << 4), g);
        }
        // weights: 9kk x 64co x 32ci = 2304 chunks
#pragma unroll
        for (int it = 0; it < 4; ++it) {
            int L = it * 576 + tid;
            int row = L >> 2, pos = L & 3;
            int kk = row >> 6, n = row & 63;
            const unsigned short* g = w2s + ((size_t)(t * 9 + kk) * 128 + co0 + n) * 64
                                      + ks * 32 + (((pos - row) & 3) << 3);
            async16(sm + 27648 + ((L & ~63) << 4), g);
        }
        __builtin_amdgcn_s_waitcnt(0);
        __syncthreads();
#pragma unroll
        for (int kk = 0; kk < 9; ++kk) {
            int kof = (kk / 3) * 26 + (kk % 3);
            bf16x8 aF2[2], bF2[4];
#pragma unroll
            for (int mt = 0; mt < 2; ++mt) {
                int ci = posA[mt] + kof;
                aF2[mt] = *(const bf16x8*)(sm + ci * 64 + ((q + ci) & 3) * 16);
            }
#pragma unroll
            for (int nt = 0; nt < 4; ++nt) {
                int r = kk * 64 + nt * 16 + lm;
                bF2[nt] = *(const bf16x8*)(sm + 27648 + r * 64 + ((q + r) & 3) * 16);
                acc[0][nt] = __builtin_amdgcn_mfma_f32_16x16x32_bf16(aF2[0], bF2[nt], acc[0][nt], 0, 0, 0);
                acc[1][nt] = __builtin_amdgcn_mfma_f32_16x16x32_bf16(aF2[1], bF2[nt], acc[1][nt], 0, 0, 0);
            }
        }
    }

    float tw = triw[t * 3 + 1], itw = 1.f / tw, cb = crb[t * 3 + 1], al = alp[t * 2 + 1];
    float apw[4] = {al * al * al * 0.25f, al * al * 0.25f, al * 0.25f, 0.25f};
    int qa = q & 1;

#pragma unroll
    for (int mt = 0; mt < 2; ++mt) {
        int tile = w * 2 + mt;
        int by = tile / 6, bx = tile % 6;
        f32x4 xq = *(const f32x4*)(sxqm + tile * 16 + q * 4);
        float s3loc[2] = {0.f, 0.f};
        unsigned short pu[4][2];
#pragma unroll
        for (int nt = 0; nt < 4; ++nt) {
            float wq = swq[nt * 16 + lm];
            float hw[4];
#pragma unroll
            for (int r = 0; r < 4; ++r) {
                float d = fmaf(-2.f, acc[mt][nt][r], xq[r]) + wq;
                d = fminf(fmaxf(d, 0.f), tw);
                float hv = 1.f - d * itw;
                hv = (hv >= cb) ? hv : 0.f;
                hw[r] = hv * apw[qa * 2 + (r & 1)];
            }
            float ph0 = hw[0] + hw[1], ph1 = hw[2] + hw[3];
            float p0 = ph0 + __shfl_xor(ph0, 16, 64);
            float p1 = ph1 + __shfl_xor(ph1, 16, 64);
            unsigned short u0 = f2bf(p0), u1 = f2bf(p1);
            float v0 = bf2f(u0), v1 = bf2f(u1);
            s3loc[0] += v0 * v0;
            s3loc[1] += v1 * v1;
            pu[nt][0] = u0; pu[nt][1] = u1;
        }
#pragma unroll
        for (int m2 = 1; m2 < 16; m2 <<= 1) {
            s3loc[0] += __shfl_xor(s3loc[0], m2, 64);
            s3loc[1] += __shfl_xor(s3loc[1], m2, 64);
        }
        if ((q & 1) == 0) {
            int py = h * 6 + by * 2 + (q >> 1);
            int px0 = bx * 2;
            int cell = (py + 1) * 14 + px0 + 1;
#pragma unroll
            for (int nt = 0; nt < 4; ++nt) {
                p2u[((size_t)i * 196 + cell) * 128 + co0 + nt * 16 + lm] = pu[nt][0];
                p2u[((size_t)i * 196 + cell + 1) * 128 + co0 + nt * 16 + lm] = pu[nt][1];
            }
            if (lm == 0) {
                atomicAdd(&S3[(size_t)i * 144 + py * 12 + px0], s3loc[0]);
                atomicAdd(&S3[(size_t)i * 144 + py * 12 + px0 + 1], s3loc[1]);
            }
        }
    }

    // border zeros: 52 cells/img split by half; this block covers its co-half
    if (tid < 208) {
        int bc_l = tid >> 3, c8 = tid & 7;
        int bc = h * 26 + bc_l;
        int cell;
        if (bc < 14) cell = bc;
        else if (bc < 28) cell = 182 + (bc - 14);
        else { int r = bc - 28; cell = (1 + (r >> 1)) * 14 + ((r & 1) * 13); }
        uint2 z; z.x = 0; z.y = 0;
        *(uint2*)(p2u + ((size_t)i * 196 + cell) * 128 + co0 + c8 * 8) = z;
        *(uint2*)(p2u + ((size_t)i * 196 + cell) * 128 + co0 + c8 * 8 + 4) = z;
    }
}

// ------------------------- conv3: 2-img MFMA GEMM -> h3 bf16 ---------------
// grid (192, 4), block 576 = 9 waves; M=288 (2 img x 144), N=64, K=4ks x 9kk x 32.
// LDS (r1 layout): img [0,27648) swizzled; w [27648,64512); sS3 64512,
// sxq3 66080, wsqh3 67232. total 67488 B. Named-reg weight ping-pong,
// 4 phases, original rotation.
#define LW3(Wv, IT, KS)                                                         \
    { int L = (IT) * 576 + tid; int row = L >> 2, pos = L & 3;                  \
      int kk = row >> 6, n = row & 63;                                          \
      Wv = *(const uint4*)(w3s + ((size_t)(t * 9 + kk) * 256 + co0 + n) * 128   \
                           + (KS) * 32 + (((pos - row) & 3) << 3)); }
#define SW(Wv, IT)                                                              \
    { int L = (IT) * 576 + tid; *(uint4*)(sm + 27648 + L * 16) = Wv; }

__global__ __launch_bounds__(576, 5) void conv3_kernel(
        const unsigned short* __restrict__ p2u, const unsigned short* __restrict__ w3s,
        const float* __restrict__ S3, const float* __restrict__ triw,
        const float* __restrict__ crb, const float* __restrict__ wsq,
        unsigned short* __restrict__ h3bf) {
    extern __shared__ char sm[];
    float* sS3   = (float*)(sm + 64512);
    float* sxq3  = (float*)(sm + 66080);
    float* wsqh3 = (float*)(sm + 67232);

    int g = blockIdx.x;
    int i0 = g * 2;
    int t = i0 / 128;
    int co0 = blockIdx.y * 64;
    int tid = threadIdx.x;
    int w = tid >> 6, l = tid & 63;
    int lm = l & 15, q = l >> 4;

    auto stimg = [&](int ks) {
#pragma unroll
        for (int it = 0; it < 3; ++it) {
            int L = it * 576 + tid;
            int Lc = (L < 1568) ? L : 0;
            int cell = Lc >> 2, pos = Lc & 3;
            int il = cell / 196, cl = cell - il * 196;
            const unsigned short* gp = p2u + ((size_t)(i0 + il) * 196 + cl) * 128
                                       + ks * 32 + (((pos - cell) & 3) << 3);
            async16(sm + ((L & ~63) << 4), gp);
        }
    };

    int posA[2], img_l[2], s0a[2];
#pragma unroll
    for (int mt = 0; mt < 2; ++mt) {
        int tb = w * 32 + mt * 16;
        int il = tb / 144, s0 = tb % 144;
        int s = s0 + lm;
        posA[mt] = il * 196 + (s / 12) * 14 + (s % 12);
        img_l[mt] = il; s0a[mt] = s0;
    }

    f32x4 zz; zz[0] = 0.f; zz[1] = 0.f; zz[2] = 0.f; zz[3] = 0.f;
    f32x4 acc[2][4];
#pragma unroll
    for (int a = 0; a < 2; ++a)
#pragma unroll
        for (int bb = 0; bb < 4; ++bb) acc[a][bb] = zz;

    auto compute = [&]() {
#pragma unroll
        for (int kk = 0; kk < 9; ++kk) {
            int kof = (kk / 3) * 14 + (kk % 3);
            bf16x8 aF3[2], bF3[4];
#pragma unroll
            for (int mt = 0; mt < 2; ++mt) {
                int ci = posA[mt] + kof;
                aF3[mt] = *(const bf16x8*)(sm + ci * 64 + ((q + ci) & 3) * 16);
            }
#pragma unroll
            for (int nt = 0; nt < 4; ++nt) {
                int r = kk * 64 + nt * 16 + lm;
                bF3[nt] = *(const bf16x8*)(sm + 27648 + r * 64 + ((q + r) & 3) * 16);
                acc[0][nt] = __builtin_amdgcn_mfma_f32_16x16x32_bf16(aF3[0], bF3[nt], acc[0][nt], 0, 0, 0);
                acc[1][nt] = __builtin_amdgcn_mfma_f32_16x16x32_bf16(aF3[1], bF3[nt], acc[1][nt], 0, 0, 0);
            }
        }
    };

    uint4 WA0, WA1, WA2, WA3, WB0, WB1, WB2, WB3;
    LW3(WA0, 0, 0) LW3(WA1, 1, 0) LW3(WA2, 2, 0) LW3(WA3, 3, 0)
    stimg(0);

    for (int e = tid; e < 392; e += 576) {
        int il = e / 196, cl = e % 196;
        int yy = cl / 14, xx = cl % 14;
        sS3[e] = (yy >= 1 && yy <= 12 && xx >= 1 && xx <= 12)
                     ? S3[(size_t)(i0 + il) * 144 + (yy - 1) * 12 + (xx - 1)] : 0.f;
    }
    if (tid < 64) wsqh3[tid] = wsq[576 + t * 256 + co0 + tid];
    __syncthreads();              // img0 + WA + prologue drained
    if (tid < 288) {
        int il = tid / 144, s = tid % 144;
        int oy = s / 12, ox = s % 12;
        float sum = 0.f;
#pragma unroll
        for (int ky = 0; ky < 3; ++ky)
#pragma unroll
            for (int kx = 0; kx < 3; ++kx)
                sum += sS3[il * 196 + (oy + ky) * 14 + (ox + kx)];
        sxq3[tid] = sum;
    }

    // phase 0
    SW(WA0, 0) SW(WA1, 1) SW(WA2, 2) SW(WA3, 3)
    __syncthreads();
    LW3(WB0, 0, 1) LW3(WB1, 1, 1) LW3(WB2, 2, 1) LW3(WB3, 3, 1)
    compute();
    // phase 1
    __syncthreads();
    stimg(1);
    SW(WB0, 0) SW(WB1, 1) SW(WB2, 2) SW(WB3, 3)
    __syncthreads();
    LW3(WA0, 0, 2) LW3(WA1, 1, 2) LW3(WA2, 2, 2) LW3(WA3, 3, 2)
    compute();
    // phase 2
    __syncthreads();
    stimg(2);
    SW(WA0, 0) SW(WA1, 1) SW(WA2, 2) SW(WA3, 3)
    __syncthreads();
    LW3(WB0, 0, 3) LW3(WB1, 1, 3) LW3(WB2, 2, 3) LW3(WB3, 3, 3)
    compute();
    // phase 3
    __syncthreads();
    stimg(3);
    SW(WB0, 0) SW(WB1, 1) SW(WB2, 2) SW(WB3, 3)
    __syncthreads();
    compute();

    __syncthreads();   // img region dead -> per-wave transpose tiles

    float tw = triw[t * 3 + 2], itw = 1.f / tw, cb = crb[t * 3 + 2];
    float* tile = (float*)(sm + w * 1280);   // 16x20 floats, wave-private
#pragma unroll
    for (int mt = 0; mt < 2; ++mt) {
        int il = img_l[mt], s0 = s0a[mt];
        int bidx = (i0 + il) - t * 128;
        unsigned short* gbase = h3bf + (size_t)bidx * 110592 + (size_t)t * 36864;
#pragma unroll
        for (int nt = 0; nt < 4; ++nt) {
            float wq = wsqh3[nt * 16 + lm];
#pragma unroll
            for (int r = 0; r < 4; ++r) {
                float d = sxq3[il * 144 + s0 + q * 4 + r] - 2.f * acc[mt][nt][r] + wq;
                d = fminf(fmaxf(d, 0.f), tw);
                float hv = 1.f - d * itw;
                hv = (hv >= cb) ? hv : 0.f;
                tile[lm * 20 + q * 4 + r] = hv;
            }
            f32x4 v = *(const f32x4*)(tile + (l >> 2) * 20 + (l & 3) * 4);
            uint2 uv; uv.x = pkbf(v[0], v[1]); uv.y = pkbf(v[2], v[3]);
            *(uint2*)(gbase + (size_t)(co0 + nt * 16 + (l >> 2)) * 144 + s0 + (l & 3) * 4) = uv;
        }
    }
}

// ------------------------- FC: LDS-free bf16 MFMA K-split (K=512) ----------
// grid 216 blocks x 512 thr; each block covers K slice [kb*512, kb*512+512).
// part halves vs K=256 split: 216 x 14336 f32 = 12.4 MB.
__global__ __launch_bounds__(512) void fc_kernel(
        const unsigned short* __restrict__ h3bf, const float* __restrict__ fcw,
        float* __restrict__ part) {
    int kb = blockIdx.x;
    int f0 = kb * 512;
    int tid = threadIdx.x;
    int w = tid >> 6, l = tid & 63;
    int lm = l & 15, q = l >> 4;

    const unsigned short* abase = h3bf + (size_t)(w * 16 + lm) * 110592 + f0 + q * 8;
    const float* brow[7];
#pragma unroll
    for (int nt = 0; nt < 7; ++nt) {
        int n = nt * 16 + lm;
        if (n > 99) n = 99;
        brow[nt] = fcw + (size_t)n * 110592 + f0 + q * 8;
    }

    f32x4 zz; zz[0] = 0.f; zz[1] = 0.f; zz[2] = 0.f; zz[3] = 0.f;
    f32x4 acc[7];
#pragma unroll
    for (int nt = 0; nt < 7; ++nt) acc[nt] = zz;

#pragma unroll 2
    for (int kc = 0; kc < 16; ++kc) {
        bf16x8 aF = *(const bf16x8*)(abase + kc * 32);
#pragma unroll
        for (int nt = 0; nt < 7; ++nt) {
            f32x4 b0 = *(const f32x4*)(brow[nt] + kc * 32);
            f32x4 b1 = *(const f32x4*)(brow[nt] + kc * 32 + 4);
            union { bf16x8 v; unsigned u[4]; } bF;
            bF.u[0] = pkbf(b0[0], b0[1]);
            bF.u[1] = pkbf(b0[2], b0[3]);
            bF.u[2] = pkbf(b1[0], b1[1]);
            bF.u[3] = pkbf(b1[2], b1[3]);
            acc[nt] = __builtin_amdgcn_mfma_f32_16x16x32_bf16(aF, bF.v, acc[nt], 0, 0, 0);
        }
    }

    float* pb = part + (size_t)kb * 14336;
#pragma unroll
    for (int nt = 0; nt < 7; ++nt)
#pragma unroll
        for (int r = 0; r < 4; ++r)
            pb[(w * 16 + q * 4 + r) * 112 + nt * 16 + lm] = acc[nt][r];
}

__global__ __launch_bounds__(256) void fc_red1_kernel(const float* __restrict__ part,
                                                      float* __restrict__ part2) {
    int c = blockIdx.x;
    int gid = blockIdx.y * 256 + threadIdx.x;
    if (gid >= 12800) return;
    const float* p = part + (size_t)(c * 27) * 14336 + (gid / 100) * 112 + gid % 100;
    float s = 0.f;
#pragma unroll 3
    for (int kb = 0; kb < 27; ++kb) s += p[(size_t)kb * 14336];
    part2[c * 12800 + gid] = s;
}

__global__ __launch_bounds__(256) void fc_red2_kernel(const float* __restrict__ part2,
                                                      const float* __restrict__ fcb,
                                                      float* __restrict__ out) {
    int gid = blockIdx.x * 256 + threadIdx.x;
    if (gid >= 12800) return;
    float s = fcb[gid % 100];
#pragma unroll
    for (int c = 0; c < 8; ++c) s += part2[c * 12800 + gid];
    out[gid] = s;
}

// ---------------------------------------------------------------------------
extern "C" void kernel_launch(void* const* d_in, const int* in_sizes, int n_in,
                              void* d_out, int out_size, void* d_ws, size_t ws_size,
                              hipStream_t stream) {
    const float* x    = (const float*)d_in[0];
    const float* W1   = (const float*)d_in[1];
    const float* W2   = (const float*)d_in[2];
    const float* W3   = (const float*)d_in[3];
    const float* triw = (const float*)d_in[4];
    const float* crb  = (const float*)d_in[5];
    const float* alp  = (const float*)d_in[6];
    const float* fcw  = (const float*)d_in[7];
    const float* fcb  = (const float*)d_in[8];
    float* out = (float*)d_out;
    float* ws  = (float*)d_ws;

    unsigned short* p1u = (unsigned short*)ws;
    unsigned short* p2u = (unsigned short*)(ws + OFF_P2CL);
    float* S2  = ws + OFF_S2;
    float* S3  = ws + OFF_S3;
    float* wsq = ws + OFF_WSQ;
    unsigned short* w2s = (unsigned short*)(ws + OFF_W2S);
    unsigned short* w3s = (unsigned short*)(ws + OFF_W3S);
    float* part  = ws + OFF_PART;
    float* part2 = ws + OFF_PART2;
    unsigned short* h3bf = (unsigned short*)ws;      // aliases p1u (dead by conv3)
    // w1s/swq1 alias head of part (dead until fc_kernel)
    unsigned short* w1s = (unsigned short*)(ws + OFF_PART);
    float* swq1 = ws + OFF_PART + 3840;

    hipFuncSetAttribute((const void*)conv2_kernel,
                        hipFuncAttributeMaxDynamicSharedMemorySize, 67376);
    hipFuncSetAttribute((const void*)conv3_kernel,
                        hipFuncAttributeMaxDynamicSharedMemorySize, 67488);

    prep_kernel<<<dim3(432), dim3(256), 0, stream>>>(W1, W2, W3, w1s, w2s, w3s, wsq, swq1, S3);
    conv1_kernel<<<dim3(384, 12), dim3(192), 0, stream>>>(x, w1s, swq1, triw, crb, alp, p1u, S2);
    conv2_kernel<<<dim3(768, 2), dim3(576), 67376, stream>>>(p1u, w2s, S2, triw, crb, alp, wsq, p2u, S3);
    conv3_kernel<<<dim3(192, 4), dim3(576), 67488, stream>>>(p2u, w3s, S3, triw, crb, wsq, h3bf);
    fc_kernel<<<dim3(216), dim3(512), 0, stream>>>(h3bf, fcw, part);
    fc_red1_kernel<<<dim3(8, 50), dim3(256), 0, stream>>>(part, part2);
    fc_red2_kernel<<<dim3(50), dim3(256), 0, stream>>>(part2, fcb, out);
}

// Round 11
// 301.695 us; speedup vs baseline: 1.0344x; 1.0344x over previous
//
#include <hip/hip_runtime.h>
#include <hip/hip_bf16.h>

// ---------------------------------------------------------------------------
// SFMCNN r10 (FINAL): best-measured configuration = r5 source (303.07us).
// conv2: r1 LDS layout, img via global_load_lds, weights global->NAMED-VGPR
// prefetch committed via ds_write (no arrays -> no scratch). conv3: 4-phase
// named-reg weight ping-pong. fc: K=256 split (grid 432). conv1: r1
// direct-fragment 192-thread blocks. Session: 374 -> ~303us; rounds 6-10
// established that conv2-variant deltas (74-85us same binary) are cross-run
// noise, so this locks the best-total config rather than best-component.
//
// ws layout (float offsets): unchanged.
//   p1u  [0, 8306688)          bf16 (3,128,26,26,64) halo-baked; h3bf aliases
//   p2u  [8306688, +4816896)   bf16 (3,128,14,14,128) halo-baked
//   S2   [13123584, +221184)   S3 [13344768, +55296)  wsq [13400064, +1344)
//   w2s  [13401408, +110592)   w3s [13512000, +442368)
//   part [13954368, +6193152)  part2 [20147520, +102400)
//   w1s/swq1 alias the head of part (dead until fc_kernel).
// ---------------------------------------------------------------------------

static const size_t OFF_P2CL = 8306688;
static const size_t OFF_S2   = 13123584;
static const size_t OFF_S3   = 13344768;
static const size_t OFF_WSQ  = 13400064;
static const size_t OFF_W2S  = 13401408;
static const size_t OFF_W3S  = 13512000;
static const size_t OFF_PART = 13954368;
static const size_t OFF_PART2= 20147520;

typedef short bf16x8 __attribute__((ext_vector_type(8)));
typedef float f32x4 __attribute__((ext_vector_type(4)));

__device__ __forceinline__ unsigned short f2bf(float f) {
    union { float f; unsigned u; } v; v.f = f;
    unsigned r = (v.u + 0x7FFFu + ((v.u >> 16) & 1u)) >> 16;
    return (unsigned short)r;
}
__device__ __forceinline__ float bf2f(unsigned short h) {
    union { unsigned u; float f; } v; v.u = ((unsigned)h) << 16;
    return v.f;
}
__device__ __forceinline__ unsigned pkbf(float a, float b) {
    union { __hip_bfloat162 h2; unsigned u; } c;
    c.h2 = __float22bfloat162_rn(make_float2(a, b));
    return c.u;
}
// async 16B/lane global->LDS; lds must be wave-uniform base (lane*16 implicit)
__device__ __forceinline__ void async16(void* lds, const void* g) {
    __builtin_amdgcn_global_load_lds(
        (const __attribute__((address_space(1))) unsigned*)g,
        (__attribute__((address_space(3))) unsigned*)lds, 16, 0, 0);
}

// ------------------------- prep: reorders + wsq + w1s + S3 zero ------------
__global__ __launch_bounds__(256) void prep_kernel(
        const float* __restrict__ W1, const float* __restrict__ W2,
        const float* __restrict__ W3,
        unsigned short* __restrict__ w1s, unsigned short* __restrict__ w2s,
        unsigned short* __restrict__ w3s,
        float* __restrict__ wsq, float* __restrict__ swq1,
        float* __restrict__ S3) {
    int gid = blockIdx.x * 256 + threadIdx.x;   // grid 432 -> 110592 threads
#pragma unroll
    for (int k = 0; k < 2; ++k) {               // W2s: (t,kk,co128,ci64)
        int e = gid * 2 + k;
        int t = e / 73728, r = e % 73728;
        int kk = r / 8192; r %= 8192;
        int co = r / 64, ci = r % 64;
        w2s[e] = f2bf(W2[(size_t)(t * 128 + co) * 576 + ci * 9 + kk]);
    }
#pragma unroll
    for (int k = 0; k < 8; ++k) {               // W3s: (t,kk,co256,ci128)
        int e = gid * 8 + k;
        int t = e / 294912, r = e % 294912;
        int kk = r / 32768; r %= 32768;
        int co = r / 128, ci = r % 128;
        w3s[e] = f2bf(W3[(size_t)(t * 256 + co) * 1152 + ci * 9 + kk]);
    }
    if (gid < 55296) S3[gid] = 0.f;
    // wsq: one wave per weight row (384 W2 rows len 576, 768 W3 rows len 1152)
    int wid = gid >> 6, lane = gid & 63;
    if (wid < 1152) {
        const float* wp; float* dst; int len;
        if (wid < 384) { wp = W2 + (size_t)wid * 576; len = 576; dst = wsq + 192 + wid; }
        else { wp = W3 + (size_t)(wid - 384) * 1152; len = 1152; dst = wsq + 576 + (wid - 384); }
        float s = 0.f;
        for (int k = lane; k < len; k += 64) { float v = bf2f(f2bf(wp[k])); s += v * v; }
#pragma unroll
        for (int m = 1; m < 64; m <<= 1) s += __shfl_xor(s, m, 64);
        if (lane == 0) *dst = s;
    }
    // w1s: (t,co) rows of 40 bf16 (25 taps + 15 zeros) + swq1
    if (gid < 192) {
        const float* wp = W1 + (size_t)(gid / 64) * 1600 + (gid % 64) * 25;
        unsigned short* dst = w1s + gid * 40;
        float s = 0.f;
        for (int k = 0; k < 25; ++k) {
            unsigned short u = f2bf(wp[k]);
            dst[k] = u; float v = bf2f(u); s += v * v;
        }
        for (int k = 25; k < 40; ++k) dst[k] = 0;
        swq1[gid] = s;
    }
}

// ------------------------- conv1: direct-fragment MFMA, fused pool + S2 ----
// grid (384 imgs, 12 tile-rows), block 192 = 3 waves, wave = 4 tiles of 4x4.
// LDS: simg [14][56] u16 (rows ty*4-2..+5 real, 8..13 zero) + sB 64x40 bf16.
__global__ __launch_bounds__(192, 6) void conv1_kernel(
        const float* __restrict__ x,
        const unsigned short* __restrict__ w1s, const float* __restrict__ swq1,
        const float* __restrict__ triw, const float* __restrict__ crb,
        const float* __restrict__ alp,
        unsigned short* __restrict__ p1u, float* __restrict__ S2) {
    __shared__ unsigned short simg[14 * 56];    // 1568 B
    __shared__ unsigned short sB[64 * 40];      // 5120 B

    int bi = blockIdx.x;
    int ty = blockIdx.y;                        // tile row 0..11
    int t = bi / 128, b = bi % 128;
    int tid = threadIdx.x;
    int w = tid >> 6, l = tid & 63;
    int lm = l & 15, q = l >> 4;
    const float* xim = x + (size_t)(b * 3 + t) * 2304;

    // stage weights (bf16-packed in prep) via async global->LDS
    {
        const unsigned short* wsrc = w1s + (size_t)t * 2560;
        for (int c = w; c < 5; c += 3)
            async16((char*)sB + c * 1024, wsrc + c * 512 + l * 8);
    }
    // stage image strip: rows 0..7 = gy ty*4-2..ty*4+5, rows 8..13 zero
    for (int idx = tid; idx < 14 * 56; idx += 192) {
        int rl = idx / 56, cc = idx % 56;
        int gy = ty * 4 - 2 + rl, gx = cc - 2;
        float v = (rl < 8 && cc < 52 && gy >= 0 && gy < 48 && gx >= 0 && gx < 48)
                      ? xim[gy * 48 + gx] : 0.f;
        simg[idx] = f2bf(v);
    }
    __syncthreads();

    f32x4 zz; zz[0] = 0.f; zz[1] = 0.f; zz[2] = 0.f; zz[3] = 0.f;
    bf16x8 bF[4];
#pragma unroll
    for (int nt = 0; nt < 4; ++nt)
        bF[nt] = *(const bf16x8*)(&sB[(nt * 16 + lm) * 40 + q * 8]);
    float wqv[4];
#pragma unroll
    for (int nt = 0; nt < 4; ++nt) wqv[nt] = swq1[t * 64 + nt * 16 + lm];

    float tw = triw[t * 3 + 0], itw = 1.f / tw;
    float cb = crb[t * 3 + 0];
    float al = alp[t * 2 + 0];
    int qa = q & 1;
    float aw0 = qa ? al * 0.25f : al * al * al * 0.25f;   // r even
    float aw1 = qa ? 0.25f      : al * al * 0.25f;        // r odd
    size_t imgbase = (size_t)bi * 43264;
    int py_g = ty * 2 + (q >> 1);
    int dx = q & 1;
    int kq = q * 8;

#pragma unroll
    for (int mt = 0; mt < 4; ++mt) {
        int tx = w * 4 + mt;
        // ---- A fragment build: row = lm (pos within tile), k-slice = q*8.. ----
        int base = ((lm >> 2) * 56 + tx * 4 + (lm & 3)) * 2;   // byte
        unsigned short rv[8];
        float sq = 0.f;
#pragma unroll
        for (int j = 0; j < 8; ++j) {
            int k = kq + j;
            int ky = (k * 205) >> 10;                 // k/5 for k<32
            int boff = 2 * k + 102 * ky;              // (ky*56 + kx)*2
            boff = (k < 25) ? boff : 10 * 112;        // k>=25 -> zero row 10
            unsigned short u = *(const unsigned short*)((const char*)simg + base + boff);
            rv[j] = u;
            float v = bf2f(u);
            sq = fmaf(v, v, sq);
        }
        sq += __shfl_xor(sq, 16, 64);
        sq += __shfl_xor(sq, 32, 64);                 // xsq of position (tx, lm)
        union { bf16x8 v; unsigned u[4]; } aF;
#pragma unroll
        for (int jj = 0; jj < 4; ++jj)
            aF.u[jj] = (unsigned)rv[2 * jj] | ((unsigned)rv[2 * jj + 1] << 16);

        f32x4 acc[4];
#pragma unroll
        for (int nt = 0; nt < 4; ++nt)
            acc[nt] = __builtin_amdgcn_mfma_f32_16x16x32_bf16(aF.v, bF[nt], zz, 0, 0, 0);

        float xr[4];
#pragma unroll
        for (int r = 0; r < 4; ++r) xr[r] = __shfl(sq, q * 4 + r, 64);

        float s2l0 = 0.f, s2l1 = 0.f;
        unsigned short pu0[4], pu1[4];
#pragma unroll
        for (int nt = 0; nt < 4; ++nt) {
            float hw[4];
#pragma unroll
            for (int r = 0; r < 4; ++r) {
                float d = fmaf(-2.f, acc[nt][r], xr[r]) + wqv[nt];
                d = fminf(fmaxf(d, 0.f), tw);
                float h = 1.f - d * itw;
                h = (h >= cb) ? h : 0.f;
                hw[r] = h * ((r & 1) ? aw1 : aw0);
            }
            float ph0 = hw[0] + hw[1], ph1 = hw[2] + hw[3];
            float p0 = ph0 + __shfl_xor(ph0, 16, 64);
            float p1 = ph1 + __shfl_xor(ph1, 16, 64);
            unsigned short u0 = f2bf(p0), u1 = f2bf(p1);
            float v0 = bf2f(u0), v1 = bf2f(u1);
            s2l0 += v0 * v0;
            s2l1 += v1 * v1;
            pu0[nt] = u0; pu1[nt] = u1;
        }
#pragma unroll
        for (int m2 = 1; m2 < 16; m2 <<= 1) {
            s2l0 += __shfl_xor(s2l0, m2, 64);
            s2l1 += __shfl_xor(s2l1, m2, 64);
        }
        int cell = (py_g + 1) * 26 + tx * 2 + 1 + dx;
#pragma unroll
        for (int nt = 0; nt < 4; ++nt)
            p1u[imgbase + (size_t)cell * 64 + nt * 16 + lm] = dx ? pu1[nt] : pu0[nt];
        if (lm == 0)
            S2[(size_t)bi * 576 + py_g * 24 + tx * 2 + dx] = dx ? s2l1 : s2l0;
    }

    // border zeros: 800 uint4 writes per img, split over 12 ty blocks
    if (tid < 68) {
        int e = ty * 68 + tid;
        if (e < 800) {
            int bc = e >> 3, c8 = e & 7;
            int cell;
            if (bc < 26) cell = bc;
            else if (bc < 52) cell = 650 + (bc - 26);
            else { int r = bc - 52; cell = (1 + (r >> 1)) * 26 + ((r & 1) * 25); }
            uint4 z; z.x = 0; z.y = 0; z.z = 0; z.w = 0;
            *(uint4*)(p1u + imgbase + (size_t)cell * 64 + c8 * 8) = z;
        }
    }
}

// ------------------------- conv2: half-image MFMA, fused pool + S3 ---------
// grid (768 = 384img x 2 halves, 2 co-halves), block 576 = 9 waves.
// M=288, N=64, K = 2ks x 9kk x 32ci. LDS (r1 layout): img [0,27648) swizzled;
// w [27648,64512) swizzled; sS 64512, sxqm 65968, swq 67120. total 67376 B.
// Weights: global->NAMED-VGPR prefetch (no arrays -> no scratch), ds_write
// commit at phase top. Best-total configuration (303.07us run).
#define LW2(Wv, IT, KS)                                                         \
    { int L = (IT) * 576 + tid; int row = L >> 2, pos = L & 3;                  \
      int kk = row >> 6, n = row & 63;                                          \
      Wv = *(const uint4*)(w2s + ((size_t)(t * 9 + kk) * 128 + co0 + n) * 64    \
                           + (KS) * 32 + (((pos - row) & 3) << 3)); }
#define SW(Wv, IT)                                                              \
    { int L = (IT) * 576 + tid; *(uint4*)(sm + 27648 + L * 16) = Wv; }

__global__ __launch_bounds__(576, 5) void conv2_kernel(
        const unsigned short* __restrict__ p1u, const unsigned short* __restrict__ w2s,
        const float* __restrict__ S2, const float* __restrict__ triw,
        const float* __restrict__ crb, const float* __restrict__ alp,
        const float* __restrict__ wsq, unsigned short* __restrict__ p2u,
        float* __restrict__ S3) {
    extern __shared__ char sm[];
    float* sS   = (float*)(sm + 64512);
    float* sxqm = (float*)(sm + 65968);
    float* swq  = (float*)(sm + 67120);

    int ih = blockIdx.x;
    int i = ih >> 1, h = ih & 1;
    int t = i / 128;
    int co0 = blockIdx.y * 64;
    int tid = threadIdx.x;
    int w = tid >> 6, l = tid & 63;
    int lm = l & 15, q = l >> 4;

    // img staging: 1456 chunks, rotation-swizzled (r1 layout)
    auto stimg = [&](int ks) {
#pragma unroll
        for (int it = 0; it < 3; ++it) {
            int L = it * 576 + tid;
            int Lc = (L < 1456) ? L : 0;
            int cell = Lc >> 2, pos = Lc & 3;
            const unsigned short* g = p1u + ((size_t)i * 676 + cell + h * 312) * 64
                                      + ks * 32 + (((pos - cell) & 3) << 3);
            async16(sm + ((L & ~63) << 4), g);
        }
    };

    int posA[2];
#pragma unroll
    for (int mt = 0; mt < 2; ++mt) {
        int tile = w * 2 + mt;
        int by = tile / 6, bx = tile % 6;
        posA[mt] = (by * 4 + (lm >> 2)) * 26 + bx * 4 + (lm & 3);
    }

    f32x4 zz; zz[0] = 0.f; zz[1] = 0.f; zz[2] = 0.f; zz[3] = 0.f;
    f32x4 acc[2][4];
#pragma unroll
    for (int a = 0; a < 2; ++a)
#pragma unroll
        for (int bb = 0; bb < 4; ++bb) acc[a][bb] = zz;

    auto compute = [&]() {
#pragma unroll
        for (int kk = 0; kk < 9; ++kk) {
            int kof = (kk / 3) * 26 + (kk % 3);
            bf16x8 aF2[2], bF2[4];
#pragma unroll
            for (int mt = 0; mt < 2; ++mt) {
                int ci = posA[mt] + kof;
                aF2[mt] = *(const bf16x8*)(sm + ci * 64 + ((q + ci) & 3) * 16);
            }
#pragma unroll
            for (int nt = 0; nt < 4; ++nt) {
                int r = kk * 64 + nt * 16 + lm;
                bF2[nt] = *(const bf16x8*)(sm + 27648 + r * 64 + ((q + r) & 3) * 16);
                acc[0][nt] = __builtin_amdgcn_mfma_f32_16x16x32_bf16(aF2[0], bF2[nt], acc[0][nt], 0, 0, 0);
                acc[1][nt] = __builtin_amdgcn_mfma_f32_16x16x32_bf16(aF2[1], bF2[nt], acc[1][nt], 0, 0, 0);
            }
        }
    };

    uint4 WA0, WA1, WA2, WA3, WB0, WB1, WB2, WB3;
    LW2(WA0, 0, 0) LW2(WA1, 1, 0) LW2(WA2, 2, 0) LW2(WA3, 3, 0)   // weights ks=0
    stimg(0);                                                      // img ks=0 async

    for (int e = tid; e < 364; e += 576) {
        int rl = e / 26, cc = e % 26;
        int gy = 12 * h + rl - 1, gx = cc - 1;
        sS[e] = (gy >= 0 && gy < 24 && gx >= 0 && gx < 24)
                    ? S2[(size_t)i * 576 + gy * 24 + gx] : 0.f;
    }
    if (tid < 64) swq[tid] = wsq[192 + t * 128 + co0 + tid];
    __syncthreads();              // #1: img0 + WA + prologue drained
    if (tid < 288) {
        int tile = tid >> 4, idx = tid & 15;
        int by = tile / 6, bx = tile % 6;
        int oy = by * 4 + (idx >> 2), ox = bx * 4 + (idx & 3);
        float s = 0.f;
#pragma unroll
        for (int ky = 0; ky < 3; ++ky)
#pragma unroll
            for (int kx = 0; kx < 3; ++kx) s += sS[(oy + ky) * 26 + ox + kx];
        sxqm[tid] = s;
    }
    SW(WA0, 0) SW(WA1, 1) SW(WA2, 2) SW(WA3, 3)                    // commit w ks=0
    __syncthreads();              // #2: weights0 visible
    LW2(WB0, 0, 1) LW2(WB1, 1, 1) LW2(WB2, 2, 1) LW2(WB3, 3, 1)    // prefetch ks=1
    compute();
    __syncthreads();              // #3: compute(0) done; WB arrived
    stimg(1);                     // img ks=1 async
    SW(WB0, 0) SW(WB1, 1) SW(WB2, 2) SW(WB3, 3)                    // commit w ks=1
    __syncthreads();              // #4: img1 + weights1 drained/visible
    compute();

    float tw = triw[t * 3 + 1], itw = 1.f / tw, cb = crb[t * 3 + 1], al = alp[t * 2 + 1];
    float apw[4] = {al * al * al * 0.25f, al * al * 0.25f, al * 0.25f, 0.25f};
    int qa = q & 1;

#pragma unroll
    for (int mt = 0; mt < 2; ++mt) {
        int tile = w * 2 + mt;
        int by = tile / 6, bx = tile % 6;
        f32x4 xq = *(const f32x4*)(sxqm + tile * 16 + q * 4);
        float s3loc[2] = {0.f, 0.f};
        unsigned short pu[4][2];
#pragma unroll
        for (int nt = 0; nt < 4; ++nt) {
            float wq = swq[nt * 16 + lm];
            float hw[4];
#pragma unroll
            for (int r = 0; r < 4; ++r) {
                float d = fmaf(-2.f, acc[mt][nt][r], xq[r]) + wq;
                d = fminf(fmaxf(d, 0.f), tw);
                float hv = 1.f - d * itw;
                hv = (hv >= cb) ? hv : 0.f;
                hw[r] = hv * apw[qa * 2 + (r & 1)];
            }
            float ph0 = hw[0] + hw[1], ph1 = hw[2] + hw[3];
            float p0 = ph0 + __shfl_xor(ph0, 16, 64);
            float p1 = ph1 + __shfl_xor(ph1, 16, 64);
            unsigned short u0 = f2bf(p0), u1 = f2bf(p1);
            float v0 = bf2f(u0), v1 = bf2f(u1);
            s3loc[0] += v0 * v0;
            s3loc[1] += v1 * v1;
            pu[nt][0] = u0; pu[nt][1] = u1;
        }
#pragma unroll
        for (int m2 = 1; m2 < 16; m2 <<= 1) {
            s3loc[0] += __shfl_xor(s3loc[0], m2, 64);
            s3loc[1] += __shfl_xor(s3loc[1], m2, 64);
        }
        if ((q & 1) == 0) {
            int py = h * 6 + by * 2 + (q >> 1);
            int px0 = bx * 2;
            int cell = (py + 1) * 14 + px0 + 1;
#pragma unroll
            for (int nt = 0; nt < 4; ++nt) {
                p2u[((size_t)i * 196 + cell) * 128 + co0 + nt * 16 + lm] = pu[nt][0];
                p2u[((size_t)i * 196 + cell + 1) * 128 + co0 + nt * 16 + lm] = pu[nt][1];
            }
            if (lm == 0) {
                atomicAdd(&S3[(size_t)i * 144 + py * 12 + px0], s3loc[0]);
                atomicAdd(&S3[(size_t)i * 144 + py * 12 + px0 + 1], s3loc[1]);
            }
        }
    }

    // border zeros: 52 cells/img split by half; this block covers its co-half
    if (tid < 208) {
        int bc_l = tid >> 3, c8 = tid & 7;
        int bc = h * 26 + bc_l;
        int cell;
        if (bc < 14) cell = bc;
        else if (bc < 28) cell = 182 + (bc - 14);
        else { int r = bc - 28; cell = (1 + (r >> 1)) * 14 + ((r & 1) * 13); }
        uint2 z; z.x = 0; z.y = 0;
        *(uint2*)(p2u + ((size_t)i * 196 + cell) * 128 + co0 + c8 * 8) = z;
        *(uint2*)(p2u + ((size_t)i * 196 + cell) * 128 + co0 + c8 * 8 + 4) = z;
    }
}

// ------------------------- conv3: 2-img MFMA GEMM -> h3 bf16 ---------------
// grid (192, 4), block 576 = 9 waves; M=288 (2 img x 144), N=64, K=4ks x 9kk x 32.
// LDS (r1 layout): img [0,27648) swizzled; w [27648,64512); sS3 64512,
// sxq3 66080, wsqh3 67232. total 67488 B. Named-reg weight ping-pong, 4 phases.
#define LW3(Wv, IT, KS)                                                         \
    { int L = (IT) * 576 + tid; int row = L >> 2, pos = L & 3;                  \
      int kk = row >> 6, n = row & 63;                                          \
      Wv = *(const uint4*)(w3s + ((size_t)(t * 9 + kk) * 256 + co0 + n) * 128   \
                           + (KS) * 32 + (((pos - row) & 3) << 3)); }

__global__ __launch_bounds__(576, 5) void conv3_kernel(
        const unsigned short* __restrict__ p2u, const unsigned short* __restrict__ w3s,
        const float* __restrict__ S3, const float* __restrict__ triw,
        const float* __restrict__ crb, const float* __restrict__ wsq,
        unsigned short* __restrict__ h3bf) {
    extern __shared__ char sm[];
    float* sS3   = (float*)(sm + 64512);
    float* sxq3  = (float*)(sm + 66080);
    float* wsqh3 = (float*)(sm + 67232);

    int g = blockIdx.x;
    int i0 = g * 2;
    int t = i0 / 128;
    int co0 = blockIdx.y * 64;
    int tid = threadIdx.x;
    int w = tid >> 6, l = tid & 63;
    int lm = l & 15, q = l >> 4;

    auto stimg = [&](int ks) {
#pragma unroll
        for (int it = 0; it < 3; ++it) {
            int L = it * 576 + tid;
            int Lc = (L < 1568) ? L : 0;
            int cell = Lc >> 2, pos = Lc & 3;
            int il = cell / 196, cl = cell - il * 196;
            const unsigned short* gp = p2u + ((size_t)(i0 + il) * 196 + cl) * 128
                                       + ks * 32 + (((pos - cell) & 3) << 3);
            async16(sm + ((L & ~63) << 4), gp);
        }
    };

    int posA[2], img_l[2], s0a[2];
#pragma unroll
    for (int mt = 0; mt < 2; ++mt) {
        int tb = w * 32 + mt * 16;
        int il = tb / 144, s0 = tb % 144;
        int s = s0 + lm;
        posA[mt] = il * 196 + (s / 12) * 14 + (s % 12);
        img_l[mt] = il; s0a[mt] = s0;
    }

    f32x4 zz; zz[0] = 0.f; zz[1] = 0.f; zz[2] = 0.f; zz[3] = 0.f;
    f32x4 acc[2][4];
#pragma unroll
    for (int a = 0; a < 2; ++a)
#pragma unroll
        for (int bb = 0; bb < 4; ++bb) acc[a][bb] = zz;

    auto compute = [&]() {
#pragma unroll
        for (int kk = 0; kk < 9; ++kk) {
            int kof = (kk / 3) * 14 + (kk % 3);
            bf16x8 aF3[2], bF3[4];
#pragma unroll
            for (int mt = 0; mt < 2; ++mt) {
                int ci = posA[mt] + kof;
                aF3[mt] = *(const bf16x8*)(sm + ci * 64 + ((q + ci) & 3) * 16);
            }
#pragma unroll
            for (int nt = 0; nt < 4; ++nt) {
                int r = kk * 64 + nt * 16 + lm;
                bF3[nt] = *(const bf16x8*)(sm + 27648 + r * 64 + ((q + r) & 3) * 16);
                acc[0][nt] = __builtin_amdgcn_mfma_f32_16x16x32_bf16(aF3[0], bF3[nt], acc[0][nt], 0, 0, 0);
                acc[1][nt] = __builtin_amdgcn_mfma_f32_16x16x32_bf16(aF3[1], bF3[nt], acc[1][nt], 0, 0, 0);
            }
        }
    };

    uint4 WA0, WA1, WA2, WA3, WB0, WB1, WB2, WB3;
    LW3(WA0, 0, 0) LW3(WA1, 1, 0) LW3(WA2, 2, 0) LW3(WA3, 3, 0)
    stimg(0);

    for (int e = tid; e < 392; e += 576) {
        int il = e / 196, cl = e % 196;
        int yy = cl / 14, xx = cl % 14;
        sS3[e] = (yy >= 1 && yy <= 12 && xx >= 1 && xx <= 12)
                     ? S3[(size_t)(i0 + il) * 144 + (yy - 1) * 12 + (xx - 1)] : 0.f;
    }
    if (tid < 64) wsqh3[tid] = wsq[576 + t * 256 + co0 + tid];
    __syncthreads();              // img0 + WA + prologue drained
    if (tid < 288) {
        int il = tid / 144, s = tid % 144;
        int oy = s / 12, ox = s % 12;
        float sum = 0.f;
#pragma unroll
        for (int ky = 0; ky < 3; ++ky)
#pragma unroll
            for (int kx = 0; kx < 3; ++kx)
                sum += sS3[il * 196 + (oy + ky) * 14 + (ox + kx)];
        sxq3[tid] = sum;
    }

    // phase 0
    SW(WA0, 0) SW(WA1, 1) SW(WA2, 2) SW(WA3, 3)
    __syncthreads();
    LW3(WB0, 0, 1) LW3(WB1, 1, 1) LW3(WB2, 2, 1) LW3(WB3, 3, 1)
    compute();
    // phase 1
    __syncthreads();
    stimg(1);
    SW(WB0, 0) SW(WB1, 1) SW(WB2, 2) SW(WB3, 3)
    __syncthreads();
    LW3(WA0, 0, 2) LW3(WA1, 1, 2) LW3(WA2, 2, 2) LW3(WA3, 3, 2)
    compute();
    // phase 2
    __syncthreads();
    stimg(2);
    SW(WA0, 0) SW(WA1, 1) SW(WA2, 2) SW(WA3, 3)
    __syncthreads();
    LW3(WB0, 0, 3) LW3(WB1, 1, 3) LW3(WB2, 2, 3) LW3(WB3, 3, 3)
    compute();
    // phase 3
    __syncthreads();
    stimg(3);
    SW(WB0, 0) SW(WB1, 1) SW(WB2, 2) SW(WB3, 3)
    __syncthreads();
    compute();

    __syncthreads();   // img region dead -> per-wave transpose tiles

    float tw = triw[t * 3 + 2], itw = 1.f / tw, cb = crb[t * 3 + 2];
    float* tile = (float*)(sm + w * 1280);   // 16x20 floats, wave-private
#pragma unroll
    for (int mt = 0; mt < 2; ++mt) {
        int il = img_l[mt], s0 = s0a[mt];
        int bidx = (i0 + il) - t * 128;
        unsigned short* gbase = h3bf + (size_t)bidx * 110592 + (size_t)t * 36864;
#pragma unroll
        for (int nt = 0; nt < 4; ++nt) {
            float wq = wsqh3[nt * 16 + lm];
#pragma unroll
            for (int r = 0; r < 4; ++r) {
                float d = sxq3[il * 144 + s0 + q * 4 + r] - 2.f * acc[mt][nt][r] + wq;
                d = fminf(fmaxf(d, 0.f), tw);
                float hv = 1.f - d * itw;
                hv = (hv >= cb) ? hv : 0.f;
                tile[lm * 20 + q * 4 + r] = hv;
            }
            f32x4 v = *(const f32x4*)(tile + (l >> 2) * 20 + (l & 3) * 4);
            uint2 uv; uv.x = pkbf(v[0], v[1]); uv.y = pkbf(v[2], v[3]);
            *(uint2*)(gbase + (size_t)(co0 + nt * 16 + (l >> 2)) * 144 + s0 + (l & 3) * 4) = uv;
        }
    }
}

// ------------------------- FC: LDS-free bf16 MFMA K-split ------------------
__global__ __launch_bounds__(512) void fc_kernel(
        const unsigned short* __restrict__ h3bf, const float* __restrict__ fcw,
        float* __restrict__ part) {
    int kb = blockIdx.x;
    int f0 = kb * 256;
    int tid = threadIdx.x;
    int w = tid >> 6, l = tid & 63;
    int lm = l & 15, q = l >> 4;

    const unsigned short* abase = h3bf + (size_t)(w * 16 + lm) * 110592 + f0 + q * 8;
    const float* brow[7];
#pragma unroll
    for (int nt = 0; nt < 7; ++nt) {
        int n = nt * 16 + lm;
        if (n > 99) n = 99;
        brow[nt] = fcw + (size_t)n * 110592 + f0 + q * 8;
    }

    f32x4 zz; zz[0] = 0.f; zz[1] = 0.f; zz[2] = 0.f; zz[3] = 0.f;
    f32x4 acc[7];
#pragma unroll
    for (int nt = 0; nt < 7; ++nt) acc[nt] = zz;

#pragma unroll 2
    for (int kc = 0; kc < 8; ++kc) {
        bf16x8 aF = *(const bf16x8*)(abase + kc * 32);
#pragma unroll
        for (int nt = 0; nt < 7; ++nt) {
            f32x4 b0 = *(const f32x4*)(brow[nt] + kc * 32);
            f32x4 b1 = *(const f32x4*)(brow[nt] + kc * 32 + 4);
            union { bf16x8 v; unsigned u[4]; } bF;
            bF.u[0] = pkbf(b0[0], b0[1]);
            bF.u[1] = pkbf(b0[2], b0[3]);
            bF.u[2] = pkbf(b1[0], b1[1]);
            bF.u[3] = pkbf(b1[2], b1[3]);
            acc[nt] = __builtin_amdgcn_mfma_f32_16x16x32_bf16(aF, bF.v, acc[nt], 0, 0, 0);
        }
    }

    float* pb = part + (size_t)kb * 14336;
#pragma unroll
    for (int nt = 0; nt < 7; ++nt)
#pragma unroll
        for (int r = 0; r < 4; ++r)
            pb[(w * 16 + q * 4 + r) * 112 + nt * 16 + lm] = acc[nt][r];
}

__global__ __launch_bounds__(256) void fc_red1_kernel(const float* __restrict__ part,
                                                      float* __restrict__ part2) {
    int c = blockIdx.x;
    int gid = blockIdx.y * 256 + threadIdx.x;
    if (gid >= 12800) return;
    const float* p = part + (size_t)(c * 54) * 14336 + (gid / 100) * 112 + gid % 100;
    float s = 0.f;
#pragma unroll 6
    for (int kb = 0; kb < 54; ++kb) s += p[(size_t)kb * 14336];
    part2[c * 12800 + gid] = s;
}

__global__ __launch_bounds__(256) void fc_red2_kernel(const float* __restrict__ part2,
                                                      const float* __restrict__ fcb,
                                                      float* __restrict__ out) {
    int gid = blockIdx.x * 256 + threadIdx.x;
    if (gid >= 12800) return;
    float s = fcb[gid % 100];
#pragma unroll
    for (int c = 0; c < 8; ++c) s += part2[c * 12800 + gid];
    out[gid] = s;
}

// ---------------------------------------------------------------------------
extern "C" void kernel_launch(void* const* d_in, const int* in_sizes, int n_in,
                              void* d_out, int out_size, void* d_ws, size_t ws_size,
                              hipStream_t stream) {
    const float* x    = (const float*)d_in[0];
    const float* W1   = (const float*)d_in[1];
    const float* W2   = (const float*)d_in[2];
    const float* W3   = (const float*)d_in[3];
    const float* triw = (const float*)d_in[4];
    const float* crb  = (const float*)d_in[5];
    const float* alp  = (const float*)d_in[6];
    const float* fcw  = (const float*)d_in[7];
    const float* fcb  = (const float*)d_in[8];
    float* out = (float*)d_out;
    float* ws  = (float*)d_ws;

    unsigned short* p1u = (unsigned short*)ws;
    unsigned short* p2u = (unsigned short*)(ws + OFF_P2CL);
    float* S2  = ws + OFF_S2;
    float* S3  = ws + OFF_S3;
    float* wsq = ws + OFF_WSQ;
    unsigned short* w2s = (unsigned short*)(ws + OFF_W2S);
    unsigned short* w3s = (unsigned short*)(ws + OFF_W3S);
    float* part  = ws + OFF_PART;
    float* part2 = ws + OFF_PART2;
    unsigned short* h3bf = (unsigned short*)ws;      // aliases p1u (dead by conv3)
    // w1s/swq1 alias head of part (dead until fc_kernel)
    unsigned short* w1s = (unsigned short*)(ws + OFF_PART);
    float* swq1 = ws + OFF_PART + 3840;

    hipFuncSetAttribute((const void*)conv2_kernel,
                        hipFuncAttributeMaxDynamicSharedMemorySize, 67376);
    hipFuncSetAttribute((const void*)conv3_kernel,
                        hipFuncAttributeMaxDynamicSharedMemorySize, 67488);

    prep_kernel<<<dim3(432), dim3(256), 0, stream>>>(W1, W2, W3, w1s, w2s, w3s, wsq, swq1, S3);
    conv1_kernel<<<dim3(384, 12), dim3(192), 0, stream>>>(x, w1s, swq1, triw, crb, alp, p1u, S2);
    conv2_kernel<<<dim3(768, 2), dim3(576), 67376, stream>>>(p1u, w2s, S2, triw, crb, alp, wsq, p2u, S3);
    conv3_kernel<<<dim3(192, 4), dim3(576), 67488, stream>>>(p2u, w3s, S3, triw, crb, wsq, h3bf);
    fc_kernel<<<dim3(432), dim3(512), 0, stream>>>(h3bf, fcw, part);
    fc_red1_kernel<<<dim3(8, 50), dim3(256), 0, stream>>>(part, part2);
    fc_red2_kernel<<<dim3(50), dim3(256), 0, stream>>>(part2, fcb, out);
}